// Round 14
// baseline (182.200 us; speedup 1.0000x reference)
//
#include <hip/hip_runtime.h>
#include <stdint.h>
#include <math.h>

#define T_SEQ 2048
#define NHEAD 16
#define WIN 256

typedef unsigned short u16;
typedef __attribute__((ext_vector_type(8))) short short8;
typedef __attribute__((ext_vector_type(4))) float f32x4;

typedef const __attribute__((address_space(1))) void* gas_ptr;
typedef __attribute__((address_space(3))) void* las_ptr;

__device__ __forceinline__ u16 f2bf(float f) {
  uint32_t u = __builtin_bit_cast(uint32_t, f);
  u += 0x7fffu + ((u >> 16) & 1u);
  return (u16)(u >> 16);
}
__device__ __forceinline__ float bf2f(u16 v) {
  return __builtin_bit_cast(float, ((uint32_t)v) << 16);
}
__device__ __forceinline__ void g2l16(const u16* g, u16* l) {
  __builtin_amdgcn_global_load_lds((gas_ptr)g, (las_ptr)l, 16, 0, 0);
}

// ---------------- fp32 -> bf16 cast (vectorized) ----------------
__global__ __launch_bounds__(256) void cast_bf16_k(const float* __restrict__ in,
                                                   u16* __restrict__ out, int n4) {
  int i = blockIdx.x * 256 + threadIdx.x;
  if (i >= n4) return;
  const float4 v = reinterpret_cast<const float4*>(in)[i];
  union { u16 h[4]; uint64_t q; } o;
  o.h[0] = f2bf(v.x); o.h[1] = f2bf(v.y); o.h[2] = f2bf(v.z); o.h[3] = f2bf(v.w);
  reinterpret_cast<uint64_t*>(out)[i] = o.q;
}

// ================= gemm1: 256x256-tile fine-interleaved pipeline ==========
// C = A[4096][1024] * B[3072][1024]^T, fused RoPE/head-split/V-transpose
// epilogue. 8 waves (2M x 4N), per-wave 128x64 output (8x4 16x16x32 frags).
// K = 32 slices of 32; LDS ring of 4 slices (A 16KB + B 16KB each = 128KB).
// Per-slice phase: vmcnt(4) -> s_barrier -> stage slice s+2 -> 12 ds_read
// -> setprio(1) 32 MFMA setprio(0). Counted vmcnt: loads span 2 phases,
// never drained (T3+T4) — except the LAST slice, which drains vmcnt(0)
// (round-13 audit: vmcnt(4) with only 4 outstanding is a no-op -> race).
// XOR swizzle col ^= (row&8)<<1 (both-sides, T2).
__device__ __forceinline__ void stage_slice(const u16* __restrict__ Ab,
                                            const u16* __restrict__ Bb,
                                            int s, u16* la, u16* lb, int tid) {
  const int w = tid >> 6, l = tid & 63;
#pragma unroll
  for (int c = 0; c < 2; c++) {
    const int rl = c * 128 + w * 16 + (l >> 2);          // row in 256-panel
    const int sc = ((l & 3) * 8) ^ ((rl & 8) << 1);      // pre-swizzled col
    const size_t so = (size_t)rl * 1024 + s * 32 + sc;
    g2l16(Ab + so, la + c * 4096 + w * 512);
    g2l16(Bb + so, lb + c * 4096 + w * 512);
  }
}

__global__ __launch_bounds__(512, 1) void gemm256_qkv(const u16* __restrict__ A,
                                                      const u16* __restrict__ B,
                                                      u16* __restrict__ Qb,
                                                      u16* __restrict__ Kb,
                                                      u16* __restrict__ Vt) {
  __shared__ u16 ringA[4][8192];
  __shared__ u16 ringB[4][8192];
  const int tid = threadIdx.x, lane = tid & 63, wave = tid >> 6;
  const int r = lane & 15, g = lane >> 4;
  const int wm = wave >> 2, wn = wave & 3;

  // XCD remap: grid 192 = 8 XCD x 24; flat ordered bn-major (B-panel reuse)
  const int flat = (blockIdx.x & 7) * 24 + (blockIdx.x >> 3);
  const int bn = flat >> 4, bm = flat & 15;   // bn in [0,12), bm in [0,16)

  const u16* Ab = A + (size_t)bm * 256 * 1024;
  const u16* Bb = B + (size_t)bn * 256 * 1024;

  f32x4 acc[8][4];
#pragma unroll
  for (int mi = 0; mi < 8; mi++)
#pragma unroll
    for (int ni = 0; ni < 4; ni++) acc[mi][ni] = (f32x4){0.f, 0.f, 0.f, 0.f};

  stage_slice(Ab, Bb, 0, ringA[0], ringB[0], tid);
  stage_slice(Ab, Bb, 1, ringA[1], ringB[1], tid);

  const int swz = (r & 8) << 1;  // read-side col XOR (row&8 == r&8 for frags)
  for (int s = 0; s < 32; ++s) {
    // own slice-s loads done; last slice must fully drain (only 4 in flight)
    if (s + 1 < 32) asm volatile("s_waitcnt vmcnt(4)" ::: "memory");
    else            asm volatile("s_waitcnt vmcnt(0)" ::: "memory");
    asm volatile("s_barrier" ::: "memory");           // all waves' s landed
    if (s + 2 < 32)
      stage_slice(Ab, Bb, s + 2, ringA[(s + 2) & 3], ringB[(s + 2) & 3], tid);

    const u16* la = ringA[s & 3];
    const u16* lb = ringB[s & 3];
    short8 af[8], bf[4];
#pragma unroll
    for (int mi = 0; mi < 8; mi++)
      af[mi] = *reinterpret_cast<const short8*>(
          &la[(wm * 128 + mi * 16 + r) * 32 + ((g * 8) ^ swz)]);
#pragma unroll
    for (int ni = 0; ni < 4; ni++)
      bf[ni] = *reinterpret_cast<const short8*>(
          &lb[(wn * 64 + ni * 16 + r) * 32 + ((g * 8) ^ swz)]);
    __builtin_amdgcn_s_setprio(1);
#pragma unroll
    for (int mi = 0; mi < 8; mi++)
#pragma unroll
      for (int ni = 0; ni < 4; ni++)
        acc[mi][ni] = __builtin_amdgcn_mfma_f32_16x16x32_bf16(af[mi], bf[ni],
                                                              acc[mi][ni], 0, 0, 0);
    __builtin_amdgcn_s_setprio(0);
  }

  // Fused epilogue: reg = bn>>2 (0=Q,1=K,2=V); head h = (bn&3)*4 + wn;
  // b = bm>>3; t = (bm&7)*256 + wm*128 + mi*16 + g*4 + j; d = ni*16 + r.
  const int reg = bn >> 2;
  const int b = bm >> 3;
  const int h = (bn & 3) * 4 + wn;
  const int bh = b * NHEAD + h;
  const int t0 = (bm & 7) * 256 + wm * 128;

  if (reg == 2) {
    u16* vb = Vt + (size_t)bh * 64 * T_SEQ;
#pragma unroll
    for (int ni = 0; ni < 4; ni++) {
      const int d = ni * 16 + r;
#pragma unroll
      for (int mi = 0; mi < 8; mi++) {
        const int t = t0 + mi * 16 + g * 4;
#pragma unroll
        for (int j = 0; j < 4; j++)
          vb[(size_t)d * T_SEQ + t + j] = f2bf(acc[mi][ni][j]);
      }
    }
  } else {
    u16* qk = (reg == 0 ? Qb : Kb) + (size_t)bh * T_SEQ * 64;
#pragma unroll
    for (int ni = 0; ni < 2; ni++) {
      const int d = ni * 16 + r;  // [0,32)
      const float inv = exp2f(-(float)d * 0.41524101186092029f);
#pragma unroll
      for (int mi = 0; mi < 8; mi++) {
        const int tb = t0 + mi * 16 + g * 4;
#pragma unroll
        for (int j = 0; j < 4; j++) {
          const int t = tb + j;
          float sn, cs;
          __sincosf((float)t * inv, &sn, &cs);
          const float x1 = acc[mi][ni][j], x2 = acc[mi][ni + 2][j];
          qk[(size_t)t * 64 + d]      = f2bf(x1 * cs - x2 * sn);
          qk[(size_t)t * 64 + d + 32] = f2bf(x2 * cs + x1 * sn);
        }
      }
    }
  }
}

// ---------------- gemm2: 128x128 NT GEMM (HW-verified round-10 structure) --
__global__ __launch_bounds__(256) void gemm_nt(const u16* __restrict__ A,
                                               const u16* __restrict__ B,
                                               float* __restrict__ C,
                                               int M, int N, int K) {
  __shared__ u16 lA[3][4096];
  __shared__ u16 lB[3][4096];
  const int tid = threadIdx.x;
  const int lane = tid & 63;
  const int wave = tid >> 6;
  const int r = lane & 15, g = lane >> 4;
  const int wr = wave >> 1, wc = wave & 1;

  const int nbn = N >> 7;            // must be divisible by 8
  const int bnpx = nbn >> 3;
  const int bid = blockIdx.x;
  const int xcd = bid & 7, ii = bid >> 3;
  const int bn = xcd * bnpx + (ii % bnpx);
  const int bm = ii / bnpx;

  const u16* Abase = A + (size_t)bm * 128 * K;
  const u16* Bbase = B + (size_t)bn * 128 * K;

  f32x4 acc[4][4];
#pragma unroll
  for (int m = 0; m < 4; m++)
#pragma unroll
    for (int n = 0; n < 4; n++) acc[m][n] = (f32x4){0.f, 0.f, 0.f, 0.f};

  const int c0 = tid, c1 = 256 + tid;
  const int row0 = c0 >> 2, row1 = c1 >> 2;
  const int sw0 = ((c0 & 3) ^ (row0 & 3)) * 8;
  const int sw1 = ((c1 & 3) ^ (row1 & 3)) * 8;
  const int ldsb = wave * 512;

  auto stage = [&](int k0, int b) {
    g2l16(Abase + (size_t)row0 * K + k0 + sw0, &lA[b][ldsb]);
    g2l16(Abase + (size_t)row1 * K + k0 + sw1, &lA[b][2048 + ldsb]);
    g2l16(Bbase + (size_t)row0 * K + k0 + sw0, &lB[b][ldsb]);
    g2l16(Bbase + (size_t)row1 * K + k0 + sw1, &lB[b][2048 + ldsb]);
  };

  const int nt = K >> 5;
  stage(0, 0);
  if (nt > 1) stage(32, 1);
  int cur = 0, pre = 2;

  const int rsw = (r & 3);
  for (int t = 0; t < nt; ++t) {
    if (t + 1 < nt) asm volatile("s_waitcnt vmcnt(4)" ::: "memory");
    else            asm volatile("s_waitcnt vmcnt(0)" ::: "memory");
    __builtin_amdgcn_s_barrier();
    if (t + 2 < nt) stage((t + 2) * 32, pre);

    const u16* la = lA[cur];
    const u16* lb = lB[cur];
    short8 af[4], bfr[4];
#pragma unroll
    for (int m = 0; m < 4; m++)
      af[m] = *reinterpret_cast<const short8*>(
          &la[(wr * 64 + m * 16 + r) * 32 + ((g ^ rsw) * 8)]);
#pragma unroll
    for (int n = 0; n < 4; n++)
      bfr[n] = *reinterpret_cast<const short8*>(
          &lb[(wc * 64 + n * 16 + r) * 32 + ((g ^ rsw) * 8)]);
#pragma unroll
    for (int m = 0; m < 4; m++)
#pragma unroll
      for (int n = 0; n < 4; n++)
        acc[m][n] = __builtin_amdgcn_mfma_f32_16x16x32_bf16(af[m], bfr[n], acc[m][n], 0, 0, 0);
    asm volatile("s_waitcnt lgkmcnt(0)" ::: "memory");
    cur = (cur == 2) ? 0 : cur + 1;
    pre = (pre == 2) ? 0 : pre + 1;
  }

#pragma unroll
  for (int m = 0; m < 4; m++) {
    const int row = bm * 128 + wr * 64 + m * 16 + g * 4;
#pragma unroll
    for (int n = 0; n < 4; n++) {
      const int col = bn * 128 + wc * 64 + n * 16 + r;
#pragma unroll
      for (int j = 0; j < 4; j++)
        C[(size_t)(row + j) * N + col] = acc[m][n][j];
    }
  }
}

// ---------------- windowed flash attention (LDS-staged, dbuf, swizzled) ----
__device__ __forceinline__ void stage_kv(const u16* __restrict__ Kh,
                                         const u16* __restrict__ Vh, int k0,
                                         u16* lk, u16* lv, int tid) {
  const int wave = tid >> 6;
#pragma unroll
  for (int p = 0; p < 2; p++) {
    int c = p * 256 + tid;
    int row = c >> 3;
    int col = ((c & 7) ^ (row & 7)) * 8;  // pre-swizzled source column
    g2l16(Kh + (size_t)(k0 + row) * 64 + col, lk + p * 2048 + wave * 512);
    g2l16(Vh + (size_t)row * T_SEQ + k0 + col, lv + p * 2048 + wave * 512);
  }
}

// grid: 1024 blocks (XCD-remapped), 4 waves; wave w owns q rows [qt*64+w*16,+16)
__global__ __launch_bounds__(256) void attn_k(const u16* __restrict__ Qb,
                                              const u16* __restrict__ Kb,
                                              const u16* __restrict__ Vt,
                                              u16* __restrict__ Ob) {
  const int bid = blockIdx.x;
  const int owned = (bid & 7) * 128 + (bid >> 3);
  const int qt = owned & 31;
  const int bh = owned >> 5;

  const int tid = threadIdx.x, lane = tid & 63, w = tid >> 6;
  const int r = lane & 15, g = lane >> 4;
  const int q0 = qt * 64;
  const u16* Qh = Qb + (size_t)bh * T_SEQ * 64;
  const u16* Kh = Kb + (size_t)bh * T_SEQ * 64;
  const u16* Vh = Vt + (size_t)bh * 64 * T_SEQ;

  __shared__ u16 lK[2][64 * 64];
  __shared__ u16 lV[2][64 * 64];
  __shared__ u16 p_lds[4][16][72];

  short8 aq[2];
#pragma unroll
  for (int kk = 0; kk < 2; kk++)
    aq[kk] = *reinterpret_cast<const short8*>(
        &Qh[(size_t)(q0 + w * 16 + r) * 64 + kk * 32 + g * 8]);

  f32x4 o[4];
#pragma unroll
  for (int n = 0; n < 4; n++) o[n] = (f32x4){0.f, 0.f, 0.f, 0.f};
  float mrun[4], lrun[4];
#pragma unroll
  for (int j = 0; j < 4; j++) { mrun[j] = -1e30f; lrun[j] = 0.f; }

  const int ktlo = (qt >= 4) ? (qt - 4) : 0;
  stage_kv(Kh, Vh, qt * 64, lK[0], lV[0], tid);
  __syncthreads();  // vmcnt(0) drain: tile qt resident
  int buf = 0;

  for (int kt = qt; kt >= ktlo; kt--) {
    const int k0 = kt * 64;
    if (kt > ktlo)
      stage_kv(Kh, Vh, (kt - 1) * 64, lK[buf ^ 1], lV[buf ^ 1], tid);

    const u16* lk = lK[buf];
    const u16* lv = lV[buf];
    const int sw = (r & 7) * 8;

    f32x4 s[4];
#pragma unroll
    for (int n = 0; n < 4; n++) {
      f32x4 sn = (f32x4){0.f, 0.f, 0.f, 0.f};
#pragma unroll
      for (int kk = 0; kk < 2; kk++) {
        short8 bk = *reinterpret_cast<const short8*>(
            &lk[(n * 16 + r) * 64 + ((kk * 32 + g * 8) ^ sw)]);
        sn = __builtin_amdgcn_mfma_f32_16x16x32_bf16(aq[kk], bk, sn, 0, 0, 0);
      }
      s[n] = sn;
    }
    float rmax[4] = {-1e30f, -1e30f, -1e30f, -1e30f};
#pragma unroll
    for (int n = 0; n < 4; n++) {
      const int k = k0 + n * 16 + r;
#pragma unroll
      for (int j = 0; j < 4; j++) {
        const int q = q0 + w * 16 + g * 4 + j;
        float v = s[n][j] * 0.125f;
        bool ok = (k <= q) && (q - k < WIN);
        v = ok ? v : -1e30f;
        s[n][j] = v;
        rmax[j] = fmaxf(rmax[j], v);
      }
    }
#pragma unroll
    for (int off = 1; off < 16; off <<= 1)
#pragma unroll
      for (int j = 0; j < 4; j++) rmax[j] = fmaxf(rmax[j], __shfl_xor(rmax[j], off));

    float scl[4];
#pragma unroll
    for (int j = 0; j < 4; j++) {
      float mn = fmaxf(mrun[j], rmax[j]);
      scl[j] = __expf(mrun[j] - mn);
      mrun[j] = mn;
    }
    float rsum[4] = {0.f, 0.f, 0.f, 0.f};
#pragma unroll
    for (int n = 0; n < 4; n++)
#pragma unroll
      for (int j = 0; j < 4; j++) {
        float p = __expf(s[n][j] - mrun[j]);
        s[n][j] = p;
        rsum[j] += p;
      }
#pragma unroll
    for (int off = 1; off < 16; off <<= 1)
#pragma unroll
      for (int j = 0; j < 4; j++) rsum[j] += __shfl_xor(rsum[j], off);
#pragma unroll
    for (int j = 0; j < 4; j++) lrun[j] = lrun[j] * scl[j] + rsum[j];
#pragma unroll
    for (int n = 0; n < 4; n++)
#pragma unroll
      for (int j = 0; j < 4; j++) o[n][j] *= scl[j];

#pragma unroll
    for (int n = 0; n < 4; n++)
#pragma unroll
      for (int j = 0; j < 4; j++) p_lds[w][g * 4 + j][n * 16 + r] = f2bf(s[n][j]);
#pragma unroll
    for (int kk = 0; kk < 2; kk++) {
      short8 ap = *reinterpret_cast<const short8*>(&p_lds[w][r][kk * 32 + g * 8]);
#pragma unroll
      for (int n = 0; n < 4; n++) {
        short8 bv = *reinterpret_cast<const short8*>(
            &lv[(n * 16 + r) * 64 + ((kk * 32 + g * 8) ^ sw)]);
        o[n] = __builtin_amdgcn_mfma_f32_16x16x32_bf16(ap, bv, o[n], 0, 0, 0);
      }
    }
    __syncthreads();
    buf ^= 1;
  }

  const int b = bh >> 4, h = bh & 15;
#pragma unroll
  for (int n = 0; n < 4; n++)
#pragma unroll
    for (int j = 0; j < 4; j++) {
      const int q = q0 + w * 16 + g * 4 + j;
      size_t off = ((size_t)(b * T_SEQ + q)) * 1024 + h * 64 + n * 16 + r;
      Ob[off] = f2bf(o[n][j] / lrun[j]);
    }
}

// ---------------- launch ----------------
extern "C" void kernel_launch(void* const* d_in, const int* in_sizes, int n_in,
                              void* d_out, int out_size, void* d_ws, size_t ws_size,
                              hipStream_t stream) {
  const float* x = (const float*)d_in[0];
  const float* w_qkv = (const float*)d_in[1];
  const float* w_out = (const float*)d_in[2];
  float* out = (float*)d_out;
  char* ws = (char*)d_ws;

  u16* xb    = (u16*)(ws + 0);          //  8 MB
  u16* wqkvb = (u16*)(ws + 8388608);    //  6 MB
  u16* Qb    = (u16*)(ws + 16777216);   //  8 MB
  u16* Kb    = (u16*)(ws + 25165824);   //  8 MB
  u16* Vt    = (u16*)(ws + 33554432);   //  8 MB
  u16* Ob    = (u16*)(ws + 41943040);   //  8 MB
  u16* woutb = (u16*)(ws + 50331648);   //  2 MB

  cast_bf16_k<<<4096, 256, 0, stream>>>(x, xb, 1048576);
  cast_bf16_k<<<3072, 256, 0, stream>>>(w_qkv, wqkvb, 786432);
  cast_bf16_k<<<1024, 256, 0, stream>>>(w_out, woutb, 262144);

  // gemm1: 256^2 fine-interleaved pipeline + fused RoPE/split/V-T epilogue
  gemm256_qkv<<<192, 512, 0, stream>>>(xb, wqkvb, Qb, Kb, Vt);

  attn_k<<<1024, 256, 0, stream>>>(Qb, Kb, Vt, Ob);

  gemm_nt<<<256, 256, 0, stream>>>(Ob, woutb, out, 4096, 1024, 1024);
}